// Round 1
// baseline (929.385 us; speedup 1.0000x reference)
//
#include <hip/hip_runtime.h>

// LSTMCell fused: out = sigmoid([sigmoid([x|h]@Wih + b_ih) | h] @ Whh + b_hh)
// B=524288, all dims 128/256. fp32 in/out, split-bf16 (hi+lo) MFMA emulation.
//
// R1: occupancy push. 16-row wave tiles (was 32):
//   - acc 32 regs (was 64), hh frags 32 (was 64), biases loaded in epilogues
//     -> total VGPR+AGPR targets <=128 bucket -> 4 waves/SIMD (launch_bounds 256,4)
//   - LDS cell[4][16][132] = 33.8 KB -> 4 blocks/CU (was 66 KB -> 2)
//   - cell is wave-private: __syncthreads removed, per-wave lgkmcnt(0) instead
//   => 8 -> 16 waves/CU; kernel is latency-bound (Mfma 19%/VALU 14%/HBM 16%).

typedef __bf16 bf16x8 __attribute__((ext_vector_type(8)));
typedef float floatx4 __attribute__((ext_vector_type(4)));

// Packed weights: [plane][fragslot][8]  plane 0=ih_hi 1=ih_lo 2=hh_hi 3=hh_lo
// fragslot = (t*8 + s)*64 + lane ; element j: W[k = s*32 + (lane>>4)*8 + j][n = t*16 + (lane&15)]
__device__ __align__(16) __bf16 g_wpack[4][4096][8];

__global__ void pack_w(const float* __restrict__ wih, const float* __restrict__ whh) {
    int tid  = blockIdx.x * 256 + threadIdx.x;   // 0..8191
    int m    = tid >> 12;                        // 0 = ih, 1 = hh
    int r    = tid & 4095;
    int lane = r & 63;
    int s    = (r >> 6) & 7;
    int t    = r >> 9;
    int quad = lane >> 4, lrow = lane & 15;
    const float* W = m ? whh : wih;
    int slot = (t * 8 + s) * 64 + lane;
#pragma unroll
    for (int j = 0; j < 8; ++j) {
        int k = s * 32 + quad * 8 + j;
        int n = t * 16 + lrow;
        float x = W[k * 128 + n];
        __bf16 h = (__bf16)x;
        __bf16 l = (__bf16)(x - (float)h);
        g_wpack[2 * m + 0][slot][j] = h;
        g_wpack[2 * m + 1][slot][j] = l;
    }
}

__device__ __forceinline__ float sigmoid_fast(float x) {
    return __builtin_amdgcn_rcpf(1.0f + __expf(-x));
}

__global__ __launch_bounds__(256, 4) void lstm_fused(
        const float* __restrict__ input_,
        const float* __restrict__ hidden,
        const float* __restrict__ bias_ih,
        const float* __restrict__ bias_hh,
        float* __restrict__ out) {
    // per-wave 16x128 cell tile; pitch 132 words -> quad rows 2-way bank alias (free)
    __shared__ __align__(16) float cell[4][16][132];

    const int wave = threadIdx.x >> 6;
    const int lane = threadIdx.x & 63;
    const int quad = lane >> 4;
    const int lrow = lane & 15;
    const long rowBase = (long)blockIdx.x * 64 + wave * 16;

    floatx4 acc[8];
#pragma unroll
    for (int t = 0; t < 8; ++t)
#pragma unroll
        for (int r = 0; r < 4; ++r)
            acc[t][r] = 0.0f;

    // hidden A-fragments kept for GEMM2 (saves a 256MB re-read)
    bf16x8 hh_hi[4], hh_lo[4];

    // ---------------- GEMM1: [input | hidden] @ Wih ----------------
#pragma unroll
    for (int s = 0; s < 8; ++s) {
        const float* src = (s < 4) ? input_ : hidden;
        const float* p = src + (rowBase + lrow) * 128 + (s & 3) * 32 + quad * 8;
        floatx4 f0 = *(const floatx4*)p;
        floatx4 f1 = *(const floatx4*)(p + 4);
        bf16x8 a_hi, a_lo;
#pragma unroll
        for (int j = 0; j < 4; ++j) {
            __bf16 h0 = (__bf16)f0[j];
            a_hi[j] = h0;
            a_lo[j] = (__bf16)(f0[j] - (float)h0);
            __bf16 h1 = (__bf16)f1[j];
            a_hi[4 + j] = h1;
            a_lo[4 + j] = (__bf16)(f1[j] - (float)h1);
        }
        if (s >= 4) { hh_hi[s - 4] = a_hi; hh_lo[s - 4] = a_lo; }
#pragma unroll
        for (int t = 0; t < 8; ++t) {
            bf16x8 bh = *(const bf16x8*)&g_wpack[0][(t * 8 + s) * 64 + lane][0];
            bf16x8 bl = *(const bf16x8*)&g_wpack[1][(t * 8 + s) * 64 + lane][0];
            acc[t] = __builtin_amdgcn_mfma_f32_16x16x32_bf16(a_hi, bh, acc[t], 0, 0, 0);
            acc[t] = __builtin_amdgcn_mfma_f32_16x16x32_bf16(a_lo, bh, acc[t], 0, 0, 0);
            acc[t] = __builtin_amdgcn_mfma_f32_16x16x32_bf16(a_hi, bl, acc[t], 0, 0, 0);
        }
    }

    // ---- epilogue 1: bias + sigmoid -> cell (LDS), reset acc ----
#pragma unroll
    for (int t = 0; t < 8; ++t) {
        float bi = bias_ih[t * 16 + lrow];
#pragma unroll
        for (int r = 0; r < 4; ++r) {
            float x = acc[t][r] + bi;
            cell[wave][quad * 4 + r][t * 16 + lrow] = sigmoid_fast(x);
            acc[t][r] = 0.0f;
        }
    }
    // cell tile is wave-private: no __syncthreads needed, just drain our LDS writes
    asm volatile("s_waitcnt lgkmcnt(0)" ::: "memory");

    // ---------------- GEMM2: [cell | hidden] @ Whh ----------------
#pragma unroll
    for (int s = 0; s < 8; ++s) {
        bf16x8 a_hi, a_lo;
        if (s < 4) {
            const float* p = &cell[wave][lrow][s * 32 + quad * 8];
            floatx4 f0 = *(const floatx4*)p;
            floatx4 f1 = *(const floatx4*)(p + 4);
#pragma unroll
            for (int j = 0; j < 4; ++j) {
                __bf16 h0 = (__bf16)f0[j];
                a_hi[j] = h0;
                a_lo[j] = (__bf16)(f0[j] - (float)h0);
                __bf16 h1 = (__bf16)f1[j];
                a_hi[4 + j] = h1;
                a_lo[4 + j] = (__bf16)(f1[j] - (float)h1);
            }
        } else {
            a_hi = hh_hi[s - 4];
            a_lo = hh_lo[s - 4];
        }
#pragma unroll
        for (int t = 0; t < 8; ++t) {
            bf16x8 bh = *(const bf16x8*)&g_wpack[2][(t * 8 + s) * 64 + lane][0];
            bf16x8 bl = *(const bf16x8*)&g_wpack[3][(t * 8 + s) * 64 + lane][0];
            acc[t] = __builtin_amdgcn_mfma_f32_16x16x32_bf16(a_hi, bh, acc[t], 0, 0, 0);
            acc[t] = __builtin_amdgcn_mfma_f32_16x16x32_bf16(a_lo, bh, acc[t], 0, 0, 0);
            acc[t] = __builtin_amdgcn_mfma_f32_16x16x32_bf16(a_hi, bl, acc[t], 0, 0, 0);
        }
    }

    // ---- epilogue 2: bias + sigmoid -> out ----
#pragma unroll
    for (int t = 0; t < 8; ++t) {
        float bh_ = bias_hh[t * 16 + lrow];
#pragma unroll
        for (int r = 0; r < 4; ++r) {
            float x = acc[t][r] + bh_;
            out[(rowBase + quad * 4 + r) * 128 + t * 16 + lrow] = sigmoid_fast(x);
        }
    }
}

extern "C" void kernel_launch(void* const* d_in, const int* in_sizes, int n_in,
                              void* d_out, int out_size, void* d_ws, size_t ws_size,
                              hipStream_t stream) {
    const float* input_ = (const float*)d_in[0];
    const float* hidden = (const float*)d_in[1];
    const float* wih    = (const float*)d_in[2];
    const float* whh    = (const float*)d_in[3];
    const float* bih    = (const float*)d_in[4];
    const float* bhh    = (const float*)d_in[5];
    float* out = (float*)d_out;

    pack_w<<<32, 256, 0, stream>>>(wih, whh);
    lstm_fused<<<8192, 256, 0, stream>>>(input_, hidden, bih, bhh, out);
}

// Round 2
// 913.658 us; speedup vs baseline: 1.0172x; 1.0172x over previous
//
#include <hip/hip_runtime.h>

// LSTMCell fused: out = sigmoid([sigmoid([x|h]@Wih + b_ih) | h] @ Whh + b_hh)
// B=524288, all dims 128/256. fp32 in/out, split-bf16 (hi+lo) MFMA emulation.
//
// R2: dual-accumulator restructure to fit 4 waves/SIMD WITHOUT spilling.
//   R1 spilled (~96B/thread, WRITE_SIZE +193MB) because hh_hi/lo frag cache
//   (32 VGPR) + acc(32) + pipelined frags > 128-reg budget.
//   Fix: while hidden frags are live in GEMM1 (s=4..7), accumulate BOTH
//     acc1 += h @ w_h   and   acc2 += h @ w_h2
//   Then GEMM2 is cell-only (s=0..3 from LDS) into acc2. No hh cache needed.
//   Peak live: 64 acc (AGPR) + ~45 transient VGPR -> fits 64V+64A @ (256,4).
//   LDS cell[4][16][132] = 33.8 KB -> 4 blocks/CU; 16 waves/CU target.

typedef __bf16 bf16x8 __attribute__((ext_vector_type(8)));
typedef float floatx4 __attribute__((ext_vector_type(4)));

// Packed weights: [plane][fragslot][8]  plane 0=ih_hi 1=ih_lo 2=hh_hi 3=hh_lo
// fragslot = (t*8 + s)*64 + lane ; element j: W[k = s*32 + (lane>>4)*8 + j][n = t*16 + (lane&15)]
__device__ __align__(16) __bf16 g_wpack[4][4096][8];

__global__ void pack_w(const float* __restrict__ wih, const float* __restrict__ whh) {
    int tid  = blockIdx.x * 256 + threadIdx.x;   // 0..8191
    int m    = tid >> 12;                        // 0 = ih, 1 = hh
    int r    = tid & 4095;
    int lane = r & 63;
    int s    = (r >> 6) & 7;
    int t    = r >> 9;
    int quad = lane >> 4, lrow = lane & 15;
    const float* W = m ? whh : wih;
    int slot = (t * 8 + s) * 64 + lane;
#pragma unroll
    for (int j = 0; j < 8; ++j) {
        int k = s * 32 + quad * 8 + j;
        int n = t * 16 + lrow;
        float x = W[k * 128 + n];
        __bf16 h = (__bf16)x;
        __bf16 l = (__bf16)(x - (float)h);
        g_wpack[2 * m + 0][slot][j] = h;
        g_wpack[2 * m + 1][slot][j] = l;
    }
}

__device__ __forceinline__ float sigmoid_fast(float x) {
    return __builtin_amdgcn_rcpf(1.0f + __expf(-x));
}

__device__ __forceinline__ void split_frag(floatx4 f0, floatx4 f1, bf16x8& a_hi, bf16x8& a_lo) {
#pragma unroll
    for (int j = 0; j < 4; ++j) {
        __bf16 h0 = (__bf16)f0[j];
        a_hi[j] = h0;
        a_lo[j] = (__bf16)(f0[j] - (float)h0);
        __bf16 h1 = (__bf16)f1[j];
        a_hi[4 + j] = h1;
        a_lo[4 + j] = (__bf16)(f1[j] - (float)h1);
    }
}

__global__ __launch_bounds__(256, 4) void lstm_fused(
        const float* __restrict__ input_,
        const float* __restrict__ hidden,
        const float* __restrict__ bias_ih,
        const float* __restrict__ bias_hh,
        float* __restrict__ out) {
    // per-wave 16x128 cell tile; pitch 132 words -> 2-way bank alias (free)
    __shared__ __align__(16) float cell[4][16][132];

    const int wave = threadIdx.x >> 6;
    const int lane = threadIdx.x & 63;
    const int quad = lane >> 4;
    const int lrow = lane & 15;
    const long rowBase = (long)blockIdx.x * 64 + wave * 16;

    floatx4 acc1[8], acc2[8];
#pragma unroll
    for (int t = 0; t < 8; ++t)
#pragma unroll
        for (int r = 0; r < 4; ++r) {
            acc1[t][r] = 0.0f;
            acc2[t][r] = 0.0f;
        }

    // ---------------- phase A: input @ w_i  (s = 0..3) ----------------
#pragma unroll
    for (int s = 0; s < 4; ++s) {
        const float* p = input_ + (rowBase + lrow) * 128 + s * 32 + quad * 8;
        floatx4 f0 = *(const floatx4*)p;
        floatx4 f1 = *(const floatx4*)(p + 4);
        bf16x8 a_hi, a_lo;
        split_frag(f0, f1, a_hi, a_lo);
#pragma unroll
        for (int t = 0; t < 8; ++t) {
            bf16x8 bh = *(const bf16x8*)&g_wpack[0][(t * 8 + s) * 64 + lane][0];
            bf16x8 bl = *(const bf16x8*)&g_wpack[1][(t * 8 + s) * 64 + lane][0];
            acc1[t] = __builtin_amdgcn_mfma_f32_16x16x32_bf16(a_hi, bh, acc1[t], 0, 0, 0);
            acc1[t] = __builtin_amdgcn_mfma_f32_16x16x32_bf16(a_lo, bh, acc1[t], 0, 0, 0);
            acc1[t] = __builtin_amdgcn_mfma_f32_16x16x32_bf16(a_hi, bl, acc1[t], 0, 0, 0);
        }
    }

    // ------- phase B: hidden @ w_h -> acc1  AND  hidden @ w_h2 -> acc2 -------
#pragma unroll
    for (int s = 4; s < 8; ++s) {
        const float* p = hidden + (rowBase + lrow) * 128 + (s - 4) * 32 + quad * 8;
        floatx4 f0 = *(const floatx4*)p;
        floatx4 f1 = *(const floatx4*)(p + 4);
        bf16x8 a_hi, a_lo;
        split_frag(f0, f1, a_hi, a_lo);
#pragma unroll
        for (int t = 0; t < 8; ++t) {
            bf16x8 bh1 = *(const bf16x8*)&g_wpack[0][(t * 8 + s) * 64 + lane][0];
            bf16x8 bl1 = *(const bf16x8*)&g_wpack[1][(t * 8 + s) * 64 + lane][0];
            acc1[t] = __builtin_amdgcn_mfma_f32_16x16x32_bf16(a_hi, bh1, acc1[t], 0, 0, 0);
            acc1[t] = __builtin_amdgcn_mfma_f32_16x16x32_bf16(a_lo, bh1, acc1[t], 0, 0, 0);
            acc1[t] = __builtin_amdgcn_mfma_f32_16x16x32_bf16(a_hi, bl1, acc1[t], 0, 0, 0);
            bf16x8 bh2 = *(const bf16x8*)&g_wpack[2][(t * 8 + s) * 64 + lane][0];
            bf16x8 bl2 = *(const bf16x8*)&g_wpack[3][(t * 8 + s) * 64 + lane][0];
            acc2[t] = __builtin_amdgcn_mfma_f32_16x16x32_bf16(a_hi, bh2, acc2[t], 0, 0, 0);
            acc2[t] = __builtin_amdgcn_mfma_f32_16x16x32_bf16(a_lo, bh2, acc2[t], 0, 0, 0);
            acc2[t] = __builtin_amdgcn_mfma_f32_16x16x32_bf16(a_hi, bl2, acc2[t], 0, 0, 0);
        }
    }

    // ---- epilogue 1: bias + sigmoid -> cell (LDS); acc1 dies here ----
#pragma unroll
    for (int t = 0; t < 8; ++t) {
        float bi = bias_ih[t * 16 + lrow];
#pragma unroll
        for (int r = 0; r < 4; ++r) {
            float x = acc1[t][r] + bi;
            cell[wave][quad * 4 + r][t * 16 + lrow] = sigmoid_fast(x);
        }
    }
    // cell tile is wave-private: no __syncthreads, just drain our LDS writes
    asm volatile("s_waitcnt lgkmcnt(0)" ::: "memory");

    // ---------------- phase C: cell @ w_c -> acc2  (s = 0..3) ----------------
#pragma unroll
    for (int s = 0; s < 4; ++s) {
        const float* p = &cell[wave][lrow][s * 32 + quad * 8];
        floatx4 f0 = *(const floatx4*)p;
        floatx4 f1 = *(const floatx4*)(p + 4);
        bf16x8 a_hi, a_lo;
        split_frag(f0, f1, a_hi, a_lo);
#pragma unroll
        for (int t = 0; t < 8; ++t) {
            bf16x8 bh = *(const bf16x8*)&g_wpack[2][(t * 8 + s) * 64 + lane][0];
            bf16x8 bl = *(const bf16x8*)&g_wpack[3][(t * 8 + s) * 64 + lane][0];
            acc2[t] = __builtin_amdgcn_mfma_f32_16x16x32_bf16(a_hi, bh, acc2[t], 0, 0, 0);
            acc2[t] = __builtin_amdgcn_mfma_f32_16x16x32_bf16(a_lo, bh, acc2[t], 0, 0, 0);
            acc2[t] = __builtin_amdgcn_mfma_f32_16x16x32_bf16(a_hi, bl, acc2[t], 0, 0, 0);
        }
    }

    // ---- epilogue 2: bias + sigmoid -> out ----
#pragma unroll
    for (int t = 0; t < 8; ++t) {
        float bh_ = bias_hh[t * 16 + lrow];
#pragma unroll
        for (int r = 0; r < 4; ++r) {
            float x = acc2[t][r] + bh_;
            out[(rowBase + quad * 4 + r) * 128 + t * 16 + lrow] = sigmoid_fast(x);
        }
    }
}

extern "C" void kernel_launch(void* const* d_in, const int* in_sizes, int n_in,
                              void* d_out, int out_size, void* d_ws, size_t ws_size,
                              hipStream_t stream) {
    const float* input_ = (const float*)d_in[0];
    const float* hidden = (const float*)d_in[1];
    const float* wih    = (const float*)d_in[2];
    const float* whh    = (const float*)d_in[3];
    const float* bih    = (const float*)d_in[4];
    const float* bhh    = (const float*)d_in[5];
    float* out = (float*)d_out;

    pack_w<<<32, 256, 0, stream>>>(wih, whh);
    lstm_fused<<<8192, 256, 0, stream>>>(input_, hidden, bih, bhh, out);
}